// Round 5
// baseline (15417.778 us; speedup 1.0000x reference)
//
#include <hip/hip_runtime.h>
#include <math.h>

#define ESN_B 16
#define ESN_T 2048
#define ESN_R 1024
#define ESN_IN 64
#define NBR (ESN_B * ESN_R)

// ---- workspace layout (float offsets) ----
#define OFF_WT_HH0 0                               // [1024][1024]  W_hh0^T
#define OFF_WT_IN1 (1024 * 1024)                   // [1024][1024]  W_in1^T
#define OFF_WT_HH1 (2 * 1024 * 1024)               // [1024][1024]  W_hh1^T
#define OFF_WT_IN0 (3 * 1024 * 1024)               // [1024][64]    W_in0^T
#define OFF_RT     (OFF_WT_IN0 + 1024 * 64)        // [64][2048]    readout^T
#define OFF_S0G    (OFF_RT + 64 * 2048)            // [2][16][1024] s0 double buffer
#define OFF_S1G    (OFF_S0G + 2 * NBR)             // [2][16][1024] s1 double buffer
#define OFF_FLAGS  (OFF_S1G + 2 * NBR)             // [4][64] f0  then  [4][64] f1

// ---------------- transpose: dst[c][r] = src[r][c] ----------------
__global__ void __launch_bounds__(256) transpose_k(const float* __restrict__ src,
                                                   float* __restrict__ dst,
                                                   int rows, int cols) {
  __shared__ float tile[32][33];
  int bx = blockIdx.x * 32, by = blockIdx.y * 32;
  int tx = threadIdx.x, ty = threadIdx.y;  // 32 x 8
  #pragma unroll
  for (int i = ty; i < 32; i += 8) {
    int r = by + i, c = bx + tx;
    if (r < rows && c < cols) tile[i][tx] = src[(size_t)r * cols + c];
  }
  __syncthreads();
  #pragma unroll
  for (int i = ty; i < 32; i += 8) {
    int c = bx + i, r = by + tx;
    if (c < cols && r < rows) dst[(size_t)c * rows + r] = tile[tx][i];
  }
}

// ---------------- helpers ----------------
__device__ __forceinline__ float fast_tanh(float v) {
  float a = fabsf(v);
  float e = __expf(-2.0f * a);
  float t = __fdividef(1.0f - e, 1.0f + e);
  return copysignf(t, v);
}

__device__ __forceinline__ float dot4(float4 a, float4 b, float acc) {
  acc = fmaf(a.x, b.x, acc);
  acc = fmaf(a.y, b.y, acc);
  acc = fmaf(a.z, b.z, acc);
  acc = fmaf(a.w, b.w, acc);
  return acc;
}

__device__ __forceinline__ float wave_red64(float v) {
  #pragma unroll
  for (int off = 32; off > 0; off >>= 1) v += __shfl_xor(v, off, 64);
  return v;
}

// 4 independent 64-lane sums with 7 shuffles; lane l returns sum for col (l&3)
__device__ __forceinline__ float reduce4(float a0, float a1, float a2, float a3,
                                         bool lb0, bool lb1) {
  float uA = lb0 ? a0 : a1, kA = lb0 ? a1 : a0;
  float A = kA + __shfl_xor(uA, 1, 64);
  float uB = lb0 ? a2 : a3, kB = lb0 ? a3 : a2;
  float B = kB + __shfl_xor(uB, 1, 64);
  float uC = lb1 ? A : B, kC = lb1 ? B : A;
  float C = kC + __shfl_xor(uC, 2, 64);
  C += __shfl_xor(C, 4, 64);
  C += __shfl_xor(C, 8, 64);
  C += __shfl_xor(C, 16, 64);
  C += __shfl_xor(C, 32, 64);
  return C;
}

// device-scope (LLC-coherent) ops: bypass L1/L2, no cache invalidates
__device__ __forceinline__ void llc_store_f32(float* p, float v) {
  asm volatile("global_store_dword %0, %1, off sc1" :: "v"(p), "v"(v) : "memory");
}
__device__ __forceinline__ void llc_store_u32(unsigned* p, unsigned v) {
  asm volatile("global_store_dword %0, %1, off sc1" :: "v"(p), "v"(v) : "memory");
}
__device__ __forceinline__ unsigned llc_load_u32(const unsigned* p) {
  unsigned f;
  asm volatile("global_load_dword %0, %1, off sc1\n\ts_waitcnt vmcnt(0)"
               : "=v"(f) : "v"(p) : "memory");
  return f;
}
__device__ __forceinline__ void vmcnt0() {
  asm volatile("s_waitcnt vmcnt(0)" ::: "memory");
}

// stage 16KB (4 rows of 1024 floats) from LLC into LDS; caller syncs
__device__ __forceinline__ void stage4k(const float* gsrc, float* ldst, int tid) {
  float4 t0, t1, t2, t3;
  const float* p = gsrc + tid * 4;
  asm volatile(
      "global_load_dwordx4 %0, %4, off sc1\n\t"
      "global_load_dwordx4 %1, %5, off sc1\n\t"
      "global_load_dwordx4 %2, %6, off sc1\n\t"
      "global_load_dwordx4 %3, %7, off sc1\n\t"
      "s_waitcnt vmcnt(0)"
      : "=&v"(t0), "=&v"(t1), "=&v"(t2), "=&v"(t3)
      : "v"(p), "v"(p + 1024), "v"(p + 2048), "v"(p + 3072)
      : "memory");
  float* d = ldst + tid * 4;
  *(float4*)(d)        = t0;
  *(float4*)(d + 1024) = t1;
  *(float4*)(d + 2048) = t2;
  *(float4*)(d + 3072) = t3;
}

// ---------------- persistent fused scan (split-flag pipeline) ----------------
// 4 groups x 64 blocks, plain launch (256 blocks on 256 CUs co-resident).
// Round r: poll f0>=r -> stage s0(r-1) -> L0(r) -> pub0   [critical chain]
//          poll f1>=r -> stage s1(r-2) -> L1(r-1) -> pub1 -> RO(r-2) [shadow]
__global__ void __launch_bounds__(256, 1) esn_scan_kernel(
    const float* __restrict__ x,
    const float* __restrict__ b0,
    const float* __restrict__ b1,
    float* __restrict__ wsf,
    float* __restrict__ out) {
  __shared__ float s0l[2][4][1024];  // slot r&1 = s0(r-1)
  __shared__ float s1l[4][1024];     // s1(r-2)

  const float* wtHH0 = wsf + OFF_WT_HH0;
  const float* wtIN1 = wsf + OFF_WT_IN1;
  const float* wtHH1 = wsf + OFF_WT_HH1;
  const float* wtIN0 = wsf + OFF_WT_IN0;
  const float* rt    = wsf + OFF_RT;
  float* s0g = wsf + OFF_S0G;
  float* s1g = wsf + OFF_S1G;
  unsigned* flags = (unsigned*)(wsf + OFF_FLAGS);

  const int tid = threadIdx.x;
  const int l = tid & 63;
  const int w = tid >> 6;
  const int bid = blockIdx.x;
  const int g = bid >> 6;        // group 0..3
  const int bg = bid & 63;       // block in group
  const int batch0 = g * 4;
  const int c0 = (bg * 4 + w) * 4;   // wave's first column
  const int wg = bg * 4 + w;         // wave idx in group 0..255
  const int rbl = wg >> 6;           // readout local batch 0..3
  const int rb = batch0 + rbl;       // readout batch
  const int roc = wg & 63;           // readout out-col
  unsigned* gflag0 = flags + g * 64;
  unsigned* gflag1 = flags + 256 + g * 64;
  const bool lb0 = (l & 1) != 0;
  const bool lb1 = (l & 2) != 0;

  // ---- persistent per-lane weights (k = q*256 + l*4 + j) ----
  float4 whh0[4][4], win1[4][4], whh1[4][4], rdt[8];
  float win0v[4];
  #pragma unroll
  for (int cc = 0; cc < 4; ++cc) {
    const float* p0 = wtHH0 + (size_t)(c0 + cc) * ESN_R + l * 4;
    const float* p1 = wtIN1 + (size_t)(c0 + cc) * ESN_R + l * 4;
    const float* p2 = wtHH1 + (size_t)(c0 + cc) * ESN_R + l * 4;
    #pragma unroll
    for (int q = 0; q < 4; ++q) {
      whh0[cc][q] = *(const float4*)(p0 + q * 256);
      win1[cc][q] = *(const float4*)(p1 + q * 256);
      whh1[cc][q] = *(const float4*)(p2 + q * 256);
    }
    win0v[cc] = wtIN0[(size_t)(c0 + cc) * ESN_IN + l];
  }
  #pragma unroll
  for (int q = 0; q < 8; ++q)
    rdt[q] = *(const float4*)(rt + (size_t)roc * 2048 + q * 256 + l * 4);
  const float b0sel = b0[c0 + (l & 3)];
  const float b1sel = b1[c0 + (l & 3)];

  for (int r = 0; r < ESN_T + 2; ++r) {
    const int slot = r & 1, oslot = slot ^ 1;
    const bool doL0 = (r < ESN_T);
    const bool doL1 = (r >= 1 && r <= ESN_T);

    // prefetch this round's x (independent of state)
    float xv[4];
    if (doL0) {
      #pragma unroll
      for (int bb = 0; bb < 4; ++bb)
        xv[bb] = x[((size_t)(batch0 + bb) * ESN_T + r) * ESN_IN + l];
    }

    // ======== CRITICAL CHAIN: s0 recurrence ========
    if (r > 0) {
      if (w == 0) {
        while (!__all(llc_load_u32(&gflag0[l]) >= (unsigned)r)) {}
      }
      __syncthreads();  // also protects s0l/s1l from restage-vs-RO race
    }

    // stage s0(r-1) -> s0l[slot]
    stage4k(s0g + oslot * NBR + batch0 * ESN_R, &s0l[slot][0][0], tid);
    __syncthreads();

    if (doL0) {
      for (int bb = 0; bb < 4; ++bb) {
        float4 h0f[4];
        #pragma unroll
        for (int q = 0; q < 4; ++q)
          h0f[q] = *(const float4*)(&s0l[slot][bb][q * 256 + l * 4]);
        float a0 = xv[bb] * win0v[0], a1 = xv[bb] * win0v[1];
        float a2 = xv[bb] * win0v[2], a3 = xv[bb] * win0v[3];
        #pragma unroll
        for (int q = 0; q < 4; ++q) {
          a0 = dot4(whh0[0][q], h0f[q], a0);
          a1 = dot4(whh0[1][q], h0f[q], a1);
          a2 = dot4(whh0[2][q], h0f[q], a2);
          a3 = dot4(whh0[3][q], h0f[q], a3);
        }
        float C = reduce4(a0, a1, a2, a3, lb0, lb1);
        if (l < 4) {
          float prev = s0l[slot][bb][c0 + l];
          float nv = 0.5f * prev + 0.5f * fast_tanh(C + b0sel);
          llc_store_f32(&s0g[slot * NBR + (batch0 + bb) * ESN_R + c0 + l], nv);
        }
      }
    }
    vmcnt0();         // this wave's s0 stores are at LLC
    __syncthreads();  // all waves' stores are at LLC
    if (tid == 0) llc_store_u32(&gflag0[bg], (unsigned)(r + 1));  // pub0

    // ======== SHADOW: s1 recurrence + readout ========
    if (r > 1) {
      if (w == 0) {
        while (!__all(llc_load_u32(&gflag1[l]) >= (unsigned)r)) {}
      }
    }
    __syncthreads();

    // stage s1(r-2) -> s1l
    stage4k(s1g + oslot * NBR + batch0 * ESN_R, &s1l[0][0], tid);
    __syncthreads();

    if (doL1) {
      for (int bb = 0; bb < 4; ++bb) {
        float4 h0f[4], h1f[4];
        #pragma unroll
        for (int q = 0; q < 4; ++q) {
          h0f[q] = *(const float4*)(&s0l[slot][bb][q * 256 + l * 4]);
          h1f[q] = *(const float4*)(&s1l[bb][q * 256 + l * 4]);
        }
        float a0 = 0.f, a1 = 0.f, a2 = 0.f, a3 = 0.f;
        #pragma unroll
        for (int q = 0; q < 4; ++q) {
          a0 = dot4(win1[0][q], h0f[q], a0); a0 = dot4(whh1[0][q], h1f[q], a0);
          a1 = dot4(win1[1][q], h0f[q], a1); a1 = dot4(whh1[1][q], h1f[q], a1);
          a2 = dot4(win1[2][q], h0f[q], a2); a2 = dot4(whh1[2][q], h1f[q], a2);
          a3 = dot4(win1[3][q], h0f[q], a3); a3 = dot4(whh1[3][q], h1f[q], a3);
        }
        float C = reduce4(a0, a1, a2, a3, lb0, lb1);
        if (l < 4) {
          float prev = s1l[bb][c0 + l];
          float nv = 0.5f * prev + 0.5f * fast_tanh(C + b1sel);
          llc_store_f32(&s1g[slot * NBR + (batch0 + bb) * ESN_R + c0 + l], nv);
        }
      }
    }
    vmcnt0();
    __syncthreads();
    if (tid == 0) llc_store_u32(&gflag1[bg], (unsigned)(r + 1));  // pub1

    // readout t = r-2: s0(r-2) = s0l[oslot] (staged last round), s1(r-2) = s1l
    if (r >= 2) {
      float a = 0.f;
      #pragma unroll
      for (int q = 0; q < 4; ++q)
        a = dot4(rdt[q], *(const float4*)(&s0l[oslot][rbl][q * 256 + l * 4]), a);
      #pragma unroll
      for (int q = 0; q < 4; ++q)
        a = dot4(rdt[q + 4], *(const float4*)(&s1l[rbl][q * 256 + l * 4]), a);
      a = wave_red64(a);
      if (l == 0) out[((size_t)rb * ESN_T + (r - 2)) * ESN_IN + roc] = a;
    }
    // next round's post-poll __syncthreads protects LDS from restaging races
  }
}

// ---------------- host launch ----------------
extern "C" void kernel_launch(void* const* d_in, const int* in_sizes, int n_in,
                              void* d_out, int out_size, void* d_ws, size_t ws_size,
                              hipStream_t stream) {
  (void)in_sizes; (void)n_in; (void)out_size; (void)ws_size;
  const float* x     = (const float*)d_in[0];
  const float* w_in0 = (const float*)d_in[1];
  const float* w_hh0 = (const float*)d_in[2];
  const float* b0    = (const float*)d_in[3];
  const float* w_in1 = (const float*)d_in[4];
  const float* w_hh1 = (const float*)d_in[5];
  const float* b1    = (const float*)d_in[6];
  const float* rdo   = (const float*)d_in[7];
  float* out = (float*)d_out;
  float* wsf = (float*)d_ws;

  dim3 tb(32, 8);
  transpose_k<<<dim3(32, 32), tb, 0, stream>>>(w_hh0, wsf + OFF_WT_HH0, 1024, 1024);
  transpose_k<<<dim3(32, 32), tb, 0, stream>>>(w_in1, wsf + OFF_WT_IN1, 1024, 1024);
  transpose_k<<<dim3(32, 32), tb, 0, stream>>>(w_hh1, wsf + OFF_WT_HH1, 1024, 1024);
  transpose_k<<<dim3(32, 2),  tb, 0, stream>>>(w_in0, wsf + OFF_WT_IN0, 64, 1024);
  transpose_k<<<dim3(2, 64),  tb, 0, stream>>>(rdo,   wsf + OFF_RT, 2048, 64);

  // zero the state slots read before first writes (r=0 reads s0g[1]; r=1 reads s1g[0])
  hipMemsetAsync(wsf + OFF_S0G + NBR, 0, NBR * sizeof(float), stream);
  hipMemsetAsync(wsf + OFF_S1G, 0, NBR * sizeof(float), stream);
  hipMemsetAsync(wsf + OFF_FLAGS, 0, 2 * 4 * 64 * sizeof(unsigned), stream);

  // plain launch: 256 blocks on 256 CUs are always co-resident
  esn_scan_kernel<<<dim3(256), dim3(256), 0, stream>>>(x, b0, b1, wsf, out);
}

// Round 6
// 13799.213 us; speedup vs baseline: 1.1173x; 1.1173x over previous
//
#include <hip/hip_runtime.h>
#include <math.h>

#define ESN_B 16
#define ESN_T 2048
#define ESN_R 1024
#define ESN_IN 64
#define NBR (ESN_B * ESN_R)

// ---- workspace layout (float offsets) ----
#define OFF_WT_HH0 0                               // [1024][1024]  W_hh0^T
#define OFF_WT_IN1 (1024 * 1024)                   // [1024][1024]  W_in1^T
#define OFF_WT_HH1 (2 * 1024 * 1024)               // [1024][1024]  W_hh1^T
#define OFF_WT_IN0 (3 * 1024 * 1024)               // [1024][64]    W_in0^T
#define OFF_RT     (OFF_WT_IN0 + 1024 * 64)        // [64][2048]    readout^T
#define OFF_S0G    (OFF_RT + 64 * 2048)            // [2][16][1024] s0 double buffer
#define OFF_S1G    (OFF_S0G + 2 * NBR)             // [2][16][1024] s1 double buffer
#define OFF_FLAGS  (OFF_S1G + 2 * NBR)             // [4][64] u32 round flags

// ---------------- transpose: dst[c][r] = src[r][c] ----------------
__global__ void __launch_bounds__(256) transpose_k(const float* __restrict__ src,
                                                   float* __restrict__ dst,
                                                   int rows, int cols) {
  __shared__ float tile[32][33];
  int bx = blockIdx.x * 32, by = blockIdx.y * 32;
  int tx = threadIdx.x, ty = threadIdx.y;  // 32 x 8
  #pragma unroll
  for (int i = ty; i < 32; i += 8) {
    int r = by + i, c = bx + tx;
    if (r < rows && c < cols) tile[i][tx] = src[(size_t)r * cols + c];
  }
  __syncthreads();
  #pragma unroll
  for (int i = ty; i < 32; i += 8) {
    int c = bx + i, r = by + tx;
    if (c < cols && r < rows) dst[(size_t)c * rows + r] = tile[tx][i];
  }
}

// ---------------- helpers ----------------
__device__ __forceinline__ float fast_tanh(float v) {
  float a = fabsf(v);
  float e = __expf(-2.0f * a);
  float t = __fdividef(1.0f - e, 1.0f + e);
  return copysignf(t, v);
}

__device__ __forceinline__ float dot4(float4 a, float4 b, float acc) {
  acc = fmaf(a.x, b.x, acc);
  acc = fmaf(a.y, b.y, acc);
  acc = fmaf(a.z, b.z, acc);
  acc = fmaf(a.w, b.w, acc);
  return acc;
}

__device__ __forceinline__ float wave_red64(float v) {
  #pragma unroll
  for (int off = 32; off > 0; off >>= 1) v += __shfl_xor(v, off, 64);
  return v;
}

// 4 independent 64-lane sums with 7 shuffles; lane l returns sum for col (l&3)
__device__ __forceinline__ float reduce4(float a0, float a1, float a2, float a3,
                                         bool lb0, bool lb1) {
  float uA = lb0 ? a0 : a1, kA = lb0 ? a1 : a0;
  float A = kA + __shfl_xor(uA, 1, 64);
  float uB = lb0 ? a2 : a3, kB = lb0 ? a3 : a2;
  float B = kB + __shfl_xor(uB, 1, 64);
  float uC = lb1 ? A : B, kC = lb1 ? B : A;
  float C = kC + __shfl_xor(uC, 2, 64);
  C += __shfl_xor(C, 4, 64);
  C += __shfl_xor(C, 8, 64);
  C += __shfl_xor(C, 16, 64);
  C += __shfl_xor(C, 32, 64);
  return C;
}

// device-scope (LLC-coherent) memory ops: bypass L1/L2, no cache invalidates
__device__ __forceinline__ void llc_store_f32(float* p, float v) {
  asm volatile("global_store_dword %0, %1, off sc1" :: "v"(p), "v"(v) : "memory");
}
__device__ __forceinline__ void llc_store_u32(unsigned* p, unsigned v) {
  asm volatile("global_store_dword %0, %1, off sc1" :: "v"(p), "v"(v) : "memory");
}
__device__ __forceinline__ unsigned llc_load_u32(const unsigned* p) {
  unsigned f;
  asm volatile("global_load_dword %0, %1, off sc1\n\ts_waitcnt vmcnt(0)"
               : "=v"(f) : "v"(p) : "memory");
  return f;
}
__device__ __forceinline__ void vmcnt0() {
  asm volatile("s_waitcnt vmcnt(0)" ::: "memory");
}

// ---------------- persistent fused scan ----------------
// 4 independent groups x 64 blocks. Group g owns batches 4g..4g+3.
// Wave = 4 cols x 4 batches, weights in registers. State staged in LDS.
// Round r: L0 -> s0(r), L1 -> s1(r-1), pub, readout -> t=r-2.
// 88KB LDS (48 static + 40 dynamic pad) forces 1 block/CU so the 256 blocks
// are always spread bijectively onto the 256 CUs (no packing stragglers).
__global__ void __launch_bounds__(256, 1) esn_scan_kernel(
    const float* __restrict__ x,
    const float* __restrict__ b0,
    const float* __restrict__ b1,
    float* __restrict__ wsf,
    float* __restrict__ out) {
  __shared__ float s0l[2][4][1024];  // s0 LDS ring: slot r&1 = s0(r-1)
  __shared__ float s1l[4][1024];     // s1(r-2)
  extern __shared__ float dyn_pad[]; // 40KB occupancy limiter (never touched)
  if (blockIdx.x == 0x7fffffffu) dyn_pad[0] = 1.0f;  // defeat DCE, never runs

  const float* wtHH0 = wsf + OFF_WT_HH0;
  const float* wtIN1 = wsf + OFF_WT_IN1;
  const float* wtHH1 = wsf + OFF_WT_HH1;
  const float* wtIN0 = wsf + OFF_WT_IN0;
  const float* rt    = wsf + OFF_RT;
  float* s0g = wsf + OFF_S0G;
  float* s1g = wsf + OFF_S1G;
  unsigned* flags = (unsigned*)(wsf + OFF_FLAGS);

  const int tid = threadIdx.x;
  const int l = tid & 63;
  const int w = tid >> 6;
  const int bid = blockIdx.x;
  const int g = bid >> 6;        // group 0..3
  const int bg = bid & 63;       // block in group
  const int batch0 = g * 4;
  const int c0 = (bg * 4 + w) * 4;   // wave's first column
  const int wg = bg * 4 + w;         // wave idx in group 0..255
  const int rbl = wg >> 6;           // readout local batch 0..3
  const int rb = batch0 + rbl;       // readout batch
  const int roc = wg & 63;           // readout out-col
  unsigned* gflags = flags + g * 64;
  const bool lb0 = (l & 1) != 0;
  const bool lb1 = (l & 2) != 0;

  // ---- persistent per-lane weights (k = q*256 + l*4 + j) ----
  float4 whh0[4][4], win1[4][4], whh1[4][4], rdt[8];
  float win0v[4];
  #pragma unroll
  for (int cc = 0; cc < 4; ++cc) {
    const float* p0 = wtHH0 + (size_t)(c0 + cc) * ESN_R + l * 4;
    const float* p1 = wtIN1 + (size_t)(c0 + cc) * ESN_R + l * 4;
    const float* p2 = wtHH1 + (size_t)(c0 + cc) * ESN_R + l * 4;
    #pragma unroll
    for (int q = 0; q < 4; ++q) {
      whh0[cc][q] = *(const float4*)(p0 + q * 256);
      win1[cc][q] = *(const float4*)(p1 + q * 256);
      whh1[cc][q] = *(const float4*)(p2 + q * 256);
    }
    win0v[cc] = wtIN0[(size_t)(c0 + cc) * ESN_IN + l];
  }
  #pragma unroll
  for (int q = 0; q < 8; ++q)
    rdt[q] = *(const float4*)(rt + (size_t)roc * 2048 + q * 256 + l * 4);
  const float b0sel = b0[c0 + (l & 3)];
  const float b1sel = b1[c0 + (l & 3)];

  for (int r = 0; r < ESN_T + 2; ++r) {
    const int slot = r & 1, oslot = slot ^ 1;
    const bool doL0 = (r < ESN_T);
    const bool doL1 = (r >= 1 && r <= ESN_T);

    // prefetch this round's x before waiting (independent of state)
    float xv[4];
    if (doL0) {
      #pragma unroll
      for (int bb = 0; bb < 4; ++bb)
        xv[bb] = x[((size_t)(batch0 + bb) * ESN_T + r) * ESN_IN + l];
    }

    // ---- wait for all blocks in group to finish round r-1 (relaxed LLC poll) ----
    if (r > 0) {
      if (w == 0) {
        while (!__all(llc_load_u32(&gflags[l]) >= (unsigned)r)) {}
      }
      __syncthreads();
    }

    // ---- stage s0(r-1) [slot] and s1(r-2) from LLC (sc1, bypass L1/L2) ----
    {
      const float* gs0 = s0g + oslot * NBR + batch0 * ESN_R + tid * 4;
      const float* gs1 = s1g + oslot * NBR + batch0 * ESN_R + tid * 4;
      float4 t0, t1, t2, t3, u0, u1, u2, u3;
      asm volatile(
          "global_load_dwordx4 %0, %8, off sc1\n\t"
          "global_load_dwordx4 %1, %9, off sc1\n\t"
          "global_load_dwordx4 %2, %10, off sc1\n\t"
          "global_load_dwordx4 %3, %11, off sc1\n\t"
          "global_load_dwordx4 %4, %12, off sc1\n\t"
          "global_load_dwordx4 %5, %13, off sc1\n\t"
          "global_load_dwordx4 %6, %14, off sc1\n\t"
          "global_load_dwordx4 %7, %15, off sc1\n\t"
          "s_waitcnt vmcnt(0)"
          : "=&v"(t0), "=&v"(t1), "=&v"(t2), "=&v"(t3),
            "=&v"(u0), "=&v"(u1), "=&v"(u2), "=&v"(u3)
          : "v"(gs0), "v"(gs0 + 1024), "v"(gs0 + 2048), "v"(gs0 + 3072),
            "v"(gs1), "v"(gs1 + 1024), "v"(gs1 + 2048), "v"(gs1 + 3072)
          : "memory");
      float* d0 = &s0l[slot][0][0] + tid * 4;
      float* d1 = &s1l[0][0] + tid * 4;
      *(float4*)(d0)        = t0;
      *(float4*)(d0 + 1024) = t1;
      *(float4*)(d0 + 2048) = t2;
      *(float4*)(d0 + 3072) = t3;
      *(float4*)(d1)        = u0;
      *(float4*)(d1 + 1024) = u1;
      *(float4*)(d1 + 2048) = u2;
      *(float4*)(d1 + 3072) = u3;
    }
    __syncthreads();

    // ---- L0 + L1 over the group's 4 batches ----
    for (int bb = 0; bb < 4; ++bb) {
      float4 h0f[4];
      #pragma unroll
      for (int q = 0; q < 4; ++q)
        h0f[q] = *(const float4*)(&s0l[slot][bb][q * 256 + l * 4]);

      if (doL0) {
        float a0 = xv[bb] * win0v[0], a1 = xv[bb] * win0v[1];
        float a2 = xv[bb] * win0v[2], a3 = xv[bb] * win0v[3];
        #pragma unroll
        for (int q = 0; q < 4; ++q) {
          a0 = dot4(whh0[0][q], h0f[q], a0);
          a1 = dot4(whh0[1][q], h0f[q], a1);
          a2 = dot4(whh0[2][q], h0f[q], a2);
          a3 = dot4(whh0[3][q], h0f[q], a3);
        }
        float C = reduce4(a0, a1, a2, a3, lb0, lb1);
        if (l < 4) {
          float prev = s0l[slot][bb][c0 + l];
          float nv = 0.5f * prev + 0.5f * fast_tanh(C + b0sel);
          llc_store_f32(&s0g[slot * NBR + (batch0 + bb) * ESN_R + c0 + l], nv);
        }
      }
      if (doL1) {
        float4 h1f[4];
        #pragma unroll
        for (int q = 0; q < 4; ++q)
          h1f[q] = *(const float4*)(&s1l[bb][q * 256 + l * 4]);
        float a0 = 0.f, a1 = 0.f, a2 = 0.f, a3 = 0.f;
        #pragma unroll
        for (int q = 0; q < 4; ++q) {
          a0 = dot4(win1[0][q], h0f[q], a0); a0 = dot4(whh1[0][q], h1f[q], a0);
          a1 = dot4(win1[1][q], h0f[q], a1); a1 = dot4(whh1[1][q], h1f[q], a1);
          a2 = dot4(win1[2][q], h0f[q], a2); a2 = dot4(whh1[2][q], h1f[q], a2);
          a3 = dot4(win1[3][q], h0f[q], a3); a3 = dot4(whh1[3][q], h1f[q], a3);
        }
        float C = reduce4(a0, a1, a2, a3, lb0, lb1);
        if (l < 4) {
          float prev = s1l[bb][c0 + l];
          float nv = 0.5f * prev + 0.5f * fast_tanh(C + b1sel);
          llc_store_f32(&s1g[slot * NBR + (batch0 + bb) * ESN_R + c0 + l], nv);
        }
      }
    }

    // ---- publish ASAP: stores at LLC (per-wave vmcnt), then flag ----
    vmcnt0();
    __syncthreads();
    if (tid == 0) llc_store_u32(&gflags[bg], (unsigned)(r + 1));

    // ---- readout t = r-2 (block-local LDS only; off the inter-block path) ----
    if (r >= 2) {
      float a = 0.f;
      #pragma unroll
      for (int q = 0; q < 4; ++q)
        a = dot4(rdt[q], *(const float4*)(&s0l[oslot][rbl][q * 256 + l * 4]), a);
      #pragma unroll
      for (int q = 0; q < 4; ++q)
        a = dot4(rdt[q + 4], *(const float4*)(&s1l[rbl][q * 256 + l * 4]), a);
      a = wave_red64(a);
      if (l == 0) out[((size_t)rb * ESN_T + (r - 2)) * ESN_IN + roc] = a;
    }
    // next round's post-poll __syncthreads protects LDS from restaging races
  }
}

// ---------------- host launch ----------------
extern "C" void kernel_launch(void* const* d_in, const int* in_sizes, int n_in,
                              void* d_out, int out_size, void* d_ws, size_t ws_size,
                              hipStream_t stream) {
  (void)in_sizes; (void)n_in; (void)out_size; (void)ws_size;
  const float* x     = (const float*)d_in[0];
  const float* w_in0 = (const float*)d_in[1];
  const float* w_hh0 = (const float*)d_in[2];
  const float* b0    = (const float*)d_in[3];
  const float* w_in1 = (const float*)d_in[4];
  const float* w_hh1 = (const float*)d_in[5];
  const float* b1    = (const float*)d_in[6];
  const float* rdo   = (const float*)d_in[7];
  float* out = (float*)d_out;
  float* wsf = (float*)d_ws;

  dim3 tb(32, 8);
  transpose_k<<<dim3(32, 32), tb, 0, stream>>>(w_hh0, wsf + OFF_WT_HH0, 1024, 1024);
  transpose_k<<<dim3(32, 32), tb, 0, stream>>>(w_in1, wsf + OFF_WT_IN1, 1024, 1024);
  transpose_k<<<dim3(32, 32), tb, 0, stream>>>(w_hh1, wsf + OFF_WT_HH1, 1024, 1024);
  transpose_k<<<dim3(32, 2),  tb, 0, stream>>>(w_in0, wsf + OFF_WT_IN0, 64, 1024);
  transpose_k<<<dim3(2, 64),  tb, 0, stream>>>(rdo,   wsf + OFF_RT, 2048, 64);

  // zero the state slots read before first writes (r=0 reads s0g[1]; r=1 reads s1g[0])
  hipMemsetAsync(wsf + OFF_S0G + NBR, 0, NBR * sizeof(float), stream);
  hipMemsetAsync(wsf + OFF_S1G, 0, NBR * sizeof(float), stream);
  hipMemsetAsync(wsf + OFF_FLAGS, 0, 4 * 64 * sizeof(unsigned), stream);

  // 40KB dynamic LDS pad -> 88KB/block total -> exactly 1 block/CU, so the
  // 256 persistent blocks are forced onto 256 distinct CUs every replay.
  esn_scan_kernel<<<dim3(256), dim3(256), 40960, stream>>>(x, b0, b1, wsf, out);
}